// Round 5
// baseline (324.420 us; speedup 1.0000x reference)
//
#include <hip/hip_runtime.h>
#include <hip/hip_bf16.h>
#include <cstddef>
#include <cstdint>

// ---------------------------------------------------------------------------
// Problem constants
// ---------------------------------------------------------------------------
#define B_   128
#define N_   8
#define C_   1024
#define FS_  14
#define POS_ 196            // 14*14
#define P_   20
#define HWC_ 9              // 3*3 cells
#define CMID_ 256
#define FEATD_ 2304         // CMID*HWC
#define H1_  1024
#define O_   27
#define PROWS_ (B_*N_*HWC_) // 9216 pooled rows (bn,cell)

typedef __attribute__((ext_vector_type(8))) short bf16x8;   // 8 bf16 (4 VGPRs)
typedef __attribute__((ext_vector_type(4))) float f32x4;

// async global->LDS, 16B per lane; LDS dest = wave-uniform base + lane*16
__device__ __forceinline__ void gld16(const void* g, void* l) {
    __builtin_amdgcn_global_load_lds(
        (const __attribute__((address_space(1))) unsigned int*)g,
        (__attribute__((address_space(3))) unsigned int*)l, 16, 0, 0);
}

// ---------------------------------------------------------------------------
// Kernel 1a: split-K partials of Wc = w2 @ w1
// ---------------------------------------------------------------------------
__global__ __launch_bounds__(256) void wcombine_split_kernel(
    const float* __restrict__ w1,   // (512,1024)
    const float* __restrict__ w2,   // (256,512)
    float* __restrict__ wpart)      // (8,256,1024) fp32
{
    const int tid = threadIdx.x;
    const int tx = tid & 15, ty = tid >> 4;
    const int c0 = blockIdx.x * 64;
    const int o0 = blockIdx.y * 64;
    const int kb = blockIdx.z * 64;
    __shared__ __align__(16) float As[16][68];
    __shared__ __align__(16) float Bs[16][68];
    float acc[4][4] = {};
    for (int k0 = kb; k0 < kb + 64; k0 += 16) {
        for (int i = tid; i < 64 * 16; i += 256) {
            int k = i & 15, m = i >> 4;
            As[k][m] = w2[(size_t)(o0 + m) * 512 + k0 + k];
        }
        for (int i = tid; i < 64 * 16; i += 256) {
            int n = i & 63, k = i >> 6;
            Bs[k][n] = w1[(size_t)(k0 + k) * 1024 + c0 + n];
        }
        __syncthreads();
        #pragma unroll
        for (int k = 0; k < 16; ++k) {
            float4 a = *(const float4*)&As[k][ty * 4];
            float4 b = *(const float4*)&Bs[k][tx * 4];
            float av[4] = {a.x, a.y, a.z, a.w};
            float bv[4] = {b.x, b.y, b.z, b.w};
            #pragma unroll
            for (int i = 0; i < 4; ++i)
                #pragma unroll
                for (int j = 0; j < 4; ++j)
                    acc[i][j] += av[i] * bv[j];
        }
        __syncthreads();
    }
    float* dst = wpart + (size_t)blockIdx.z * (256 * 1024);
    for (int i = 0; i < 4; ++i) {
        float4 v = make_float4(acc[i][0], acc[i][1], acc[i][2], acc[i][3]);
        *(float4*)&dst[(size_t)(o0 + ty * 4 + i) * 1024 + c0 + tx * 4] = v;
    }
}

// ---------------------------------------------------------------------------
// Kernel 1b: Wc = bf16( sum_z wpart[z] )
// ---------------------------------------------------------------------------
__global__ __launch_bounds__(256) void wc_reduce_kernel(
    const float* __restrict__ wpart, __hip_bfloat16* __restrict__ Wc)
{
    int idx = blockIdx.x * 256 + threadIdx.x;
    float s = 0.f;
    #pragma unroll
    for (int z = 0; z < 8; ++z) s += wpart[(size_t)z * (256 * 1024) + idx];
    Wc[idx] = __float2bfloat16(s);
}

// ---------------------------------------------------------------------------
// Kernel tapw (NEW): precompute ROI-align tap table per (bn, cell):
//   16 entries {pos index, weight}. Weight folds the 0.25 mean factor and
//   the validity mask. Hoists all coordinate math (clamp/floor/cvt/min)
//   out of roipool, where it was replicated 64 lanes x 16 c-blocks.
// ---------------------------------------------------------------------------
__global__ __launch_bounds__(256) void tapw_kernel(
    const float* __restrict__ boxes,   // (128,8,4)
    int* __restrict__ tpos,            // (9216,16) element indices
    float* __restrict__ twt)           // (9216,16) weights
{
    int idx = blockIdx.x * 256 + threadIdx.x;   // bn*9+cell
    if (idx >= PROWS_) return;
    int bn = idx / 9, cell = idx - bn * 9;
    int chh = cell / 3, cww = cell % 3;
    const float* bx = boxes + (size_t)bn * 4;
    float x1 = bx[0], y1 = bx[1], x2 = bx[2], y2 = bx[3];
    float bw = (x2 - x1) * (1.0f / 3.0f);
    float bh = (y2 - y1) * (1.0f / 3.0f);
    int* pd = tpos + (size_t)idx * 16;
    float* wd = twt + (size_t)idx * 16;
    int o = 0;
    #pragma unroll
    for (int si = 0; si < 2; ++si) {
        float yy = y1 + ((float)(2 * chh + si) + 0.5f) * 0.5f * bh;
        #pragma unroll
        for (int sj = 0; sj < 2; ++sj) {
            float xx = x1 + ((float)(2 * cww + sj) + 0.5f) * 0.5f * bw;
            bool valid = (yy > -1.0f) && (yy < (float)FS_) &&
                         (xx > -1.0f) && (xx < (float)FS_);
            float y = fminf(fmaxf(yy, 0.0f), (float)(FS_ - 1));
            float x = fminf(fmaxf(xx, 0.0f), (float)(FS_ - 1));
            int y0 = (int)floorf(y);
            int x0 = (int)floorf(x);
            int y1i = min(y0 + 1, FS_ - 1);
            int x1i = min(x0 + 1, FS_ - 1);
            float ly = y - (float)y0, lx = x - (float)x0;
            float hy = 1.0f - ly,     hx = 1.0f - lx;
            float q = valid ? 0.25f : 0.0f;
            pd[o + 0] = y0  * FS_ + x0 ;  wd[o + 0] = hy * hx * q;
            pd[o + 1] = y0  * FS_ + x1i;  wd[o + 1] = hy * lx * q;
            pd[o + 2] = y1i * FS_ + x0 ;  wd[o + 2] = ly * hx * q;
            pd[o + 3] = y1i * FS_ + x1i;  wd[o + 3] = ly * lx * q;
            o += 4;
        }
    }
}

// ---------------------------------------------------------------------------
// Kernel 2: roipool — ROI-align directly on raw fmap (fp32) using the
//   precomputed tap table. Per (b, 64-channel chunk):
//   - fmap[b][c][pos] read coalesced (float4 along pos), exactly once.
//   - LDS tile [64 c][197] fp32 (stride 197: tap reads lane=c are 2-way
//     bank-aliased = free; staging-write conflicts measured at only ~3 µs).
//   - compute: 16 fmac per cell, weights via SGPR loads (readfirstlane
//     forces the table index scalar -> s_load_dwordx16), acc fp32.
//   Round-4 PMC: 60 µs, VALUBusy 32%, hbm 14% -> VALU/instruction-bound on
//   per-tap coordinate math (wave-uniform AND replicated x16 c-blocks).
//   The table removes ~2.5x of the per-thread VALU work.
// ---------------------------------------------------------------------------
#define CCH_  64
#define LSTR_ 197
__global__ __launch_bounds__(256, 3) void roipool_kernel(
    const float* __restrict__ fmap,          // (128,1024,196)
    const int* __restrict__ tpos,            // (9216,16)
    const float* __restrict__ twt,           // (9216,16)
    __hip_bfloat16* __restrict__ pooled)     // (9216, 1024)
{
    const int b  = blockIdx.y;
    const int c0 = blockIdx.x * CCH_;
    const int tid = threadIdx.x;
    __shared__ float Ls[CCH_ * LSTR_];       // 50.4 KB -> 3 blocks/CU

    // stage: 64 c-rows x 49 float4 (= 196 pos)
    const float* src = fmap + ((size_t)b * C_ + c0) * POS_;
    for (int i = tid; i < CCH_ * 49; i += 256) {
        int c = i / 49, ch = i - c * 49;
        float4 v = *(const float4*)(src + (size_t)c * POS_ + ch * 4);
        float* dst = &Ls[c * LSTR_ + ch * 4];
        dst[0] = v.x; dst[1] = v.y; dst[2] = v.z; dst[3] = v.w;
    }
    __syncthreads();

    const int cl = tid & 63;                 // channel lane
    const int ng = tid >> 6;                 // wave id -> boxes {2ng, 2ng+1}
    const float* lsc = &Ls[cl * LSTR_];
    // wave-uniform (tid>>6 is constant across the wave) -> SGPR
    const int bn0 = __builtin_amdgcn_readfirstlane(b * N_ + ng * 2);

    #pragma unroll
    for (int nn = 0; nn < 2; ++nn) {
        const int bn = bn0 + nn;
        __hip_bfloat16* prow = pooled + (size_t)(bn * HWC_) * C_ + c0 + cl;
        #pragma unroll
        for (int cell = 0; cell < 9; ++cell) {
            const int te = (bn * HWC_ + cell) * 16;
            const int*   pp = tpos + te;     // uniform -> s_load
            const float* ww = twt + te;      // uniform -> s_load
            float acc = 0.0f;
            #pragma unroll
            for (int i = 0; i < 16; ++i)
                acc = fmaf(ww[i], lsc[pp[i]], acc);
            prow[(size_t)cell * C_] = __float2bfloat16(acc);
        }
    }
}

// ---------------------------------------------------------------------------
// Kernel 3: pooledgemm — feat = pooled @ Wc^T, fp32 out.
//   M=9216, N=256, K=1024; both operands K-contiguous bf16, gld16 staging.
// ---------------------------------------------------------------------------
__global__ __launch_bounds__(256, 4) void pooledgemm_kernel(
    const __hip_bfloat16* __restrict__ A,    // pooled (9216 x 1024)
    const __hip_bfloat16* __restrict__ Bm,   // Wc (256 x 1024)
    float* __restrict__ Cout)                // feat (9216 x 256) fp32
{
    const int tid = threadIdx.x;
    const int wave = tid >> 6, lane = tid & 63;
    const int r0 = blockIdx.y * 64, n0 = blockIdx.x * 64;
    const int wm = (wave >> 1) * 32, wn = (wave & 1) * 32;
    const int m16 = lane & 15, quad = lane >> 4;
    const int K = C_;
    __shared__ __align__(16) __hip_bfloat16 As[64 * 64];
    __shared__ __align__(16) __hip_bfloat16 Bs[64 * 64];

    f32x4 acc[2][2];
    #pragma unroll
    for (int i = 0; i < 2; ++i)
        #pragma unroll
        for (int j = 0; j < 2; ++j)
            acc[i][j] = (f32x4){0.f, 0.f, 0.f, 0.f};

    const int qa = wave * 64 + lane;                 // 0..255
    const int ms0 = qa >> 3, cs0 = (qa & 7) ^ (ms0 & 7);
    const int qb1 = qa + 256;
    const int ms1 = qb1 >> 3, cs1 = (qb1 & 7) ^ (ms1 & 7);
    const size_t rA0 = (size_t)(r0 + ms0) * K + cs0 * 8;
    const size_t rA1 = (size_t)(r0 + ms1) * K + cs1 * 8;
    const size_t rB0 = (size_t)(n0 + ms0) * K + cs0 * 8;
    const size_t rB1 = (size_t)(n0 + ms1) * K + cs1 * 8;

    for (int k0 = 0; k0 < K; k0 += 64) {
        gld16(A  + rA0 + k0, &As[wave * 512]);
        gld16(Bm + rB0 + k0, &Bs[wave * 512]);
        gld16(A  + rA1 + k0, &As[2048 + wave * 512]);
        gld16(Bm + rB1 + k0, &Bs[2048 + wave * 512]);
        __syncthreads();
        #pragma unroll
        for (int ks = 0; ks < 2; ++ks) {
            bf16x8 af[2], bfv[2];
            #pragma unroll
            for (int t = 0; t < 2; ++t) {
                int m = wm + t * 16 + m16;
                int cp = (ks * 4 + quad) ^ (m & 7);
                af[t] = *(const bf16x8*)&As[(m * 8 + cp) * 8];
                int n = wn + t * 16 + m16;
                int cq = (ks * 4 + quad) ^ (n & 7);
                bfv[t] = *(const bf16x8*)&Bs[(n * 8 + cq) * 8];
            }
            #pragma unroll
            for (int i = 0; i < 2; ++i)
                #pragma unroll
                for (int j = 0; j < 2; ++j)
                    acc[i][j] = __builtin_amdgcn_mfma_f32_16x16x32_bf16(
                        af[i], bfv[j], acc[i][j], 0, 0, 0);
        }
        __syncthreads();
    }

    #pragma unroll
    for (int i = 0; i < 2; ++i) {
        #pragma unroll
        for (int j = 0; j < 2; ++j) {
            int col = n0 + wn + j * 16 + m16;
            int rbase = r0 + wm + i * 16 + quad * 4;
            #pragma unroll
            for (int g = 0; g < 4; ++g)
                Cout[(size_t)(rbase + g) * 256 + col] = acc[i][j][g];
        }
    }
}

// ---------------------------------------------------------------------------
// MFMA GEMM (fc1): h1 = relu(diff @ fc1_wp^T + b). 32x64 tile, BK=64.
// ---------------------------------------------------------------------------
__global__ __launch_bounds__(256, 4) void fc1_gemm_kernel(
    const __hip_bfloat16* __restrict__ A,    // diff (1024 x 2304)
    const __hip_bfloat16* __restrict__ Bm,   // fc1_wp (1024 x 2304)
    const float* __restrict__ bias,
    float* __restrict__ C)                   // h1 (1024 x 1024)
{
    const int tid = threadIdx.x;
    const int wave = tid >> 6, lane = tid & 63;
    const int r0 = blockIdx.y * 32, n0 = blockIdx.x * 64;
    const int wm = (wave >> 1) * 16, wn = (wave & 1) * 32;
    const int m16 = lane & 15, quad = lane >> 4;
    const int K = FEATD_;
    __shared__ __align__(16) __hip_bfloat16 As[32 * 64];
    __shared__ __align__(16) __hip_bfloat16 Bs[64 * 64];

    f32x4 acc[2];
    acc[0] = (f32x4){0.f, 0.f, 0.f, 0.f};
    acc[1] = (f32x4){0.f, 0.f, 0.f, 0.f};

    const int qa = wave * 64 + lane;                 // 0..255
    const int msA = qa >> 3, csA = (qa & 7) ^ (msA & 7);
    const int qb1 = qa + 256;
    const int msB1 = qb1 >> 3, csB1 = (qb1 & 7) ^ (msB1 & 7);
    const size_t rA  = (size_t)(r0 + msA)  * K + csA  * 8;
    const size_t rB0 = (size_t)(n0 + msA)  * K + csA  * 8;
    const size_t rB1 = (size_t)(n0 + msB1) * K + csB1 * 8;

    for (int k0 = 0; k0 < K; k0 += 64) {
        gld16(A  + rA  + k0, &As[wave * 512]);
        gld16(Bm + rB0 + k0, &Bs[wave * 512]);
        gld16(Bm + rB1 + k0, &Bs[2048 + wave * 512]);
        __syncthreads();
        #pragma unroll
        for (int ks = 0; ks < 2; ++ks) {
            bf16x8 af, bfv[2];
            int m = wm + m16;
            int cp = (ks * 4 + quad) ^ (m & 7);
            af = *(const bf16x8*)&As[(m * 8 + cp) * 8];
            #pragma unroll
            for (int t = 0; t < 2; ++t) {
                int n = wn + t * 16 + m16;
                int cq = (ks * 4 + quad) ^ (n & 7);
                bfv[t] = *(const bf16x8*)&Bs[(n * 8 + cq) * 8];
            }
            #pragma unroll
            for (int j = 0; j < 2; ++j)
                acc[j] = __builtin_amdgcn_mfma_f32_16x16x32_bf16(
                    af, bfv[j], acc[j], 0, 0, 0);
        }
        __syncthreads();
    }

    #pragma unroll
    for (int j = 0; j < 2; ++j) {
        int col = n0 + wn + j * 16 + m16;
        int rbase = r0 + wm + quad * 4;
        float bv = bias[col];
        #pragma unroll
        for (int g = 0; g < 4; ++g) {
            int r = rbase + g;
            float v = acc[j][g] + bv;
            C[(size_t)r * H1_ + col] = v > 0.f ? v : 0.f;
        }
    }
}

// ---------------------------------------------------------------------------
// fc1_w (1024 x 2304 fp32, k = o*9+hw) -> bf16 permuted (k' = hw*256+o)
// ---------------------------------------------------------------------------
__global__ __launch_bounds__(256) void fc1w_perm_kernel(
    const float* __restrict__ src, __hip_bfloat16* __restrict__ dst)
{
    int h = blockIdx.x;
    int tid = threadIdx.x;
    __shared__ float buf[FEATD_];
    const float* s = src + (size_t)h * FEATD_;
    #pragma unroll
    for (int it = 0; it < 9; ++it)
        buf[it * 256 + tid] = s[it * 256 + tid];
    __syncthreads();
    __hip_bfloat16* d = dst + (size_t)h * FEATD_;
    #pragma unroll
    for (int it = 0; it < 9; ++it) {
        int dd = it * 256 + tid;       // hw = it, o = tid
        d[dd] = __float2bfloat16(buf[tid * HWC_ + it]);
    }
}

// ---------------------------------------------------------------------------
// inv[b][p] = n with pids[b][n]==p else -1
// ---------------------------------------------------------------------------
__global__ __launch_bounds__(64) void invmap_kernel(
    const int* __restrict__ pids, int* __restrict__ inv)
{
    int b = blockIdx.x;
    int p = threadIdx.x;
    if (p < P_) {
        int v = -1;
        for (int n = 0; n < N_; ++n)
            if (pids[b * N_ + n] == p) v = n;
        inv[b * P_ + p] = v;
    }
}

// ---------------------------------------------------------------------------
// mean_b[p][d] = (1/128) sum_b feat[b, inv[b][p], d]
// ---------------------------------------------------------------------------
__global__ __launch_bounds__(256) void meanb_kernel(
    const float* __restrict__ feat, const int* __restrict__ inv,
    float* __restrict__ mean_b)
{
    int p = blockIdx.x;
    int d = blockIdx.y * 256 + threadIdx.x;
    float acc = 0.0f;
    #pragma unroll 4
    for (int b = 0; b < B_; ++b) {
        int n = inv[b * P_ + p];
        if (n >= 0) acc += feat[(size_t)(b * N_ + n) * FEATD_ + d];
    }
    mean_b[(size_t)p * FEATD_ + d] = acc * (1.0f / (float)B_);
}

// ---------------------------------------------------------------------------
// diff_bf16[r][d] = bf16(mean_b[pids[r]][d] - feat[r][d])
// ---------------------------------------------------------------------------
__global__ __launch_bounds__(256) void diff_kernel(
    const float* __restrict__ feat, const float* __restrict__ mean_b,
    const int* __restrict__ pids, __hip_bfloat16* __restrict__ diff)
{
    int r = blockIdx.x;
    int pid = pids[r];
    const float* fr = feat + (size_t)r * FEATD_;
    const float* mr = mean_b + (size_t)pid * FEATD_;
    __hip_bfloat16* dr = diff + (size_t)r * FEATD_;
    for (int d = threadIdx.x; d < FEATD_; d += 256)
        dr[d] = __float2bfloat16(mr[d] - fr[d]);
}

// ---------------------------------------------------------------------------
// fc2: out[bn][o] = h1[bn] . fc2_w[o] + fc2_b[o]
// ---------------------------------------------------------------------------
__global__ __launch_bounds__(256) void fc2_kernel(
    const float* __restrict__ h1, const float* __restrict__ fc2_w,
    const float* __restrict__ fc2_b, float* __restrict__ out)
{
    int bn = blockIdx.x;
    int tid = threadIdx.x;
    __shared__ __align__(16) float row[H1_];
    __shared__ float partial[32][8];
    ((float4*)row)[tid] = ((const float4*)(h1 + (size_t)bn * H1_))[tid];
    __syncthreads();
    int o = tid >> 3, part = tid & 7;
    float acc = 0.0f;
    if (o < O_) {
        const float* wrow = fc2_w + (size_t)o * H1_ + part * 128;
        const float* hrow = row + part * 128;
        #pragma unroll 4
        for (int j = 0; j < 128; ++j) acc += hrow[j] * wrow[j];
    }
    partial[o][part] = acc;
    __syncthreads();
    if (part == 0 && o < O_) {
        float s = fc2_b[o];
        #pragma unroll
        for (int p = 0; p < 8; ++p) s += partial[o][p];
        out[(size_t)bn * O_ + o] = s;
    }
}

// ---------------------------------------------------------------------------
// Launch
// ---------------------------------------------------------------------------
extern "C" void kernel_launch(void* const* d_in, const int* in_sizes, int n_in,
                              void* d_out, int out_size, void* d_ws, size_t ws_size,
                              hipStream_t stream) {
    const float* fmap  = (const float*)d_in[0];
    const float* boxes = (const float*)d_in[1];
    const int*   pids  = (const int*)  d_in[2];
    const float* w1    = (const float*)d_in[3];
    const float* w2    = (const float*)d_in[4];
    const float* fc1_w = (const float*)d_in[5];
    const float* fc1_b = (const float*)d_in[6];
    const float* fc2_w = (const float*)d_in[7];
    const float* fc2_b = (const float*)d_in[8];
    float* out = (float*)d_out;

    // workspace layout (all 16B aligned)
    char* wsb = (char*)d_ws;
    __hip_bfloat16* Wc     = (__hip_bfloat16*)wsb;                      // 256*1024
    __hip_bfloat16* pooled = Wc + 256 * 1024;                           // 9216*1024
    __hip_bfloat16* fc1wp  = pooled + (size_t)PROWS_ * C_;              // 1024*2304
    __hip_bfloat16* diffp  = fc1wp + (size_t)H1_ * FEATD_;              // 1024*2304
    float* feat   = (float*)(diffp + (size_t)H1_ * FEATD_);             // 1024*2304
    float* mean_b = feat + (size_t)(B_ * N_) * FEATD_;                  // 20*2304
    float* h1     = mean_b + (size_t)P_ * FEATD_;                       // 1024*1024
    int*   inv    = (int*)(h1 + (size_t)(B_ * N_) * H1_);               // 128*20
    float* wpart  = (float*)(inv + 128 * P_ + 64);                      // 8*256*1024
    int*   tpos   = (int*)(wpart + 8 * 256 * 1024);                     // 9216*16
    float* twt    = (float*)(tpos + (size_t)PROWS_ * 16);               // 9216*16

    hipLaunchKernelGGL(tapw_kernel, dim3(36), dim3(256), 0, stream,
                       boxes, tpos, twt);
    hipLaunchKernelGGL(wcombine_split_kernel, dim3(16, 4, 8), dim3(256), 0, stream,
                       w1, w2, wpart);
    hipLaunchKernelGGL(wc_reduce_kernel, dim3(1024), dim3(256), 0, stream,
                       wpart, Wc);
    hipLaunchKernelGGL(roipool_kernel, dim3(16, 128), dim3(256), 0, stream,
                       fmap, tpos, twt, pooled);
    hipLaunchKernelGGL(pooledgemm_kernel, dim3(4, 144), dim3(256), 0, stream,
                       pooled, Wc, feat);
    hipLaunchKernelGGL(fc1w_perm_kernel, dim3(1024), dim3(256), 0, stream,
                       fc1_w, fc1wp);
    hipLaunchKernelGGL(invmap_kernel, dim3(128), dim3(64), 0, stream,
                       pids, inv);
    hipLaunchKernelGGL(meanb_kernel, dim3(20, 9), dim3(256), 0, stream,
                       feat, inv, mean_b);
    hipLaunchKernelGGL(diff_kernel, dim3(1024), dim3(256), 0, stream,
                       feat, mean_b, pids, diffp);
    hipLaunchKernelGGL(fc1_gemm_kernel, dim3(16, 32), dim3(256), 0, stream,
                       diffp, fc1wp, fc1_b, h1);
    hipLaunchKernelGGL(fc2_kernel, dim3(1024), dim3(256), 0, stream,
                       h1, fc2_w, fc2_b, out);
}

// Round 6
// 294.281 us; speedup vs baseline: 1.1024x; 1.1024x over previous
//
#include <hip/hip_runtime.h>
#include <hip/hip_bf16.h>
#include <cstddef>
#include <cstdint>

// ---------------------------------------------------------------------------
// Problem constants
// ---------------------------------------------------------------------------
#define B_   128
#define N_   8
#define C_   1024
#define FS_  14
#define POS_ 196            // 14*14
#define P_   20
#define HWC_ 9              // 3*3 cells
#define CMID_ 256
#define FEATD_ 2304         // CMID*HWC
#define H1_  1024
#define O_   27
#define PROWS_ (B_*N_*HWC_) // 9216 pooled rows (bn,cell)

typedef __attribute__((ext_vector_type(8))) short bf16x8;   // 8 bf16 (4 VGPRs)
typedef __attribute__((ext_vector_type(4))) float f32x4;

// async global->LDS, 16B per lane; LDS dest = wave-uniform base + lane*16
__device__ __forceinline__ void gld16(const void* g, void* l) {
    __builtin_amdgcn_global_load_lds(
        (const __attribute__((address_space(1))) unsigned int*)g,
        (__attribute__((address_space(3))) unsigned int*)l, 16, 0, 0);
}

// ---------------------------------------------------------------------------
// Kernel 1a: split-K partials of Wc = w2 @ w1
// ---------------------------------------------------------------------------
__global__ __launch_bounds__(256) void wcombine_split_kernel(
    const float* __restrict__ w1,   // (512,1024)
    const float* __restrict__ w2,   // (256,512)
    float* __restrict__ wpart)      // (8,256,1024) fp32
{
    const int tid = threadIdx.x;
    const int tx = tid & 15, ty = tid >> 4;
    const int c0 = blockIdx.x * 64;
    const int o0 = blockIdx.y * 64;
    const int kb = blockIdx.z * 64;
    __shared__ __align__(16) float As[16][68];
    __shared__ __align__(16) float Bs[16][68];
    float acc[4][4] = {};
    for (int k0 = kb; k0 < kb + 64; k0 += 16) {
        for (int i = tid; i < 64 * 16; i += 256) {
            int k = i & 15, m = i >> 4;
            As[k][m] = w2[(size_t)(o0 + m) * 512 + k0 + k];
        }
        for (int i = tid; i < 64 * 16; i += 256) {
            int n = i & 63, k = i >> 6;
            Bs[k][n] = w1[(size_t)(k0 + k) * 1024 + c0 + n];
        }
        __syncthreads();
        #pragma unroll
        for (int k = 0; k < 16; ++k) {
            float4 a = *(const float4*)&As[k][ty * 4];
            float4 b = *(const float4*)&Bs[k][tx * 4];
            float av[4] = {a.x, a.y, a.z, a.w};
            float bv[4] = {b.x, b.y, b.z, b.w};
            #pragma unroll
            for (int i = 0; i < 4; ++i)
                #pragma unroll
                for (int j = 0; j < 4; ++j)
                    acc[i][j] += av[i] * bv[j];
        }
        __syncthreads();
    }
    float* dst = wpart + (size_t)blockIdx.z * (256 * 1024);
    for (int i = 0; i < 4; ++i) {
        float4 v = make_float4(acc[i][0], acc[i][1], acc[i][2], acc[i][3]);
        *(float4*)&dst[(size_t)(o0 + ty * 4 + i) * 1024 + c0 + tx * 4] = v;
    }
}

// ---------------------------------------------------------------------------
// Kernel 1b: Wc = bf16( sum_z wpart[z] )
// ---------------------------------------------------------------------------
__global__ __launch_bounds__(256) void wc_reduce_kernel(
    const float* __restrict__ wpart, __hip_bfloat16* __restrict__ Wc)
{
    int idx = blockIdx.x * 256 + threadIdx.x;
    float s = 0.f;
    #pragma unroll
    for (int z = 0; z < 8; ++z) s += wpart[(size_t)z * (256 * 1024) + idx];
    Wc[idx] = __float2bfloat16(s);
}

// ---------------------------------------------------------------------------
// Kernel 2: roipool — ROI-align directly on raw fmap (fp32), inline tap math.
//   Round-5 post-mortem: tap TABLE regressed (global s_loads added latency
//   to a latency-bound kernel: VALUBusy 32->16% but dur 60->89 µs).
//   Round-4 counters (60 µs): VALU 32%, HBM 14%, occupancy 27% (=3 blocks/CU,
//   LDS-capped at 50.7 KB) -> latency-bound, needs TLP, not less VALU.
//   This version: CCH 64->32 (LDS 25.2 KB -> 6 blocks/CU, launch_bounds(256,6),
//   grid 4096 blocks), one box per 32-lane group (tid>>5), lane = channel.
//   - fmap[b][c0..c0+31][*] staged as one contiguous 100 KB read (float4).
//   - LDS stride 197 (== 5 mod 32, gcd(5,32)=1): tap reads 2-way = free.
//   - identical fp32 tap expression/order as round 4 -> absmax unchanged.
// ---------------------------------------------------------------------------
#define CCH_  32
#define LSTR_ 197
__global__ __launch_bounds__(256, 6) void roipool_kernel(
    const float* __restrict__ fmap,          // (128,1024,196)
    const float* __restrict__ boxes,         // (128,8,4)
    __hip_bfloat16* __restrict__ pooled)     // (9216, 1024)
{
    const int b  = blockIdx.y;
    const int c0 = blockIdx.x * CCH_;
    const int tid = threadIdx.x;
    __shared__ float Ls[CCH_ * LSTR_];       // 25.2 KB -> 6 blocks/CU

    // stage: 32 c-rows x 49 float4 (= 196 pos); source region is contiguous
    const float* src = fmap + ((size_t)b * C_ + c0) * POS_;
    for (int i = tid; i < CCH_ * 49; i += 256) {
        int c = i / 49, ch = i - c * 49;
        float4 v = *(const float4*)(src + (size_t)c * POS_ + ch * 4);
        float* dst = &Ls[c * LSTR_ + ch * 4];
        dst[0] = v.x; dst[1] = v.y; dst[2] = v.z; dst[3] = v.w;
    }
    __syncthreads();

    const int cl = tid & 31;                 // channel lane
    const int n  = tid >> 5;                 // box 0..7
    const float* lsc = &Ls[cl * LSTR_];

    const float* bx = boxes + ((size_t)b * N_ + n) * 4;
    float x1 = bx[0], y1 = bx[1], x2 = bx[2], y2 = bx[3];
    float bw = (x2 - x1) * (1.0f / 3.0f);
    float bh = (y2 - y1) * (1.0f / 3.0f);
    __hip_bfloat16* prow = pooled + (size_t)((b * N_ + n) * HWC_) * C_ + c0 + cl;

    #pragma unroll
    for (int cell = 0; cell < 9; ++cell) {
        const int chh = cell / 3, cww = cell % 3;
        float acc = 0.0f;
        #pragma unroll
        for (int si = 0; si < 2; ++si) {
            float yy = y1 + ((float)(2 * chh + si) + 0.5f) * 0.5f * bh;
            #pragma unroll
            for (int sj = 0; sj < 2; ++sj) {
                float xx = x1 + ((float)(2 * cww + sj) + 0.5f) * 0.5f * bw;
                bool valid = (yy > -1.0f) && (yy < (float)FS_) &&
                             (xx > -1.0f) && (xx < (float)FS_);
                float y = fminf(fmaxf(yy, 0.0f), (float)(FS_ - 1));
                float x = fminf(fmaxf(xx, 0.0f), (float)(FS_ - 1));
                int y0 = (int)floorf(y);
                int x0 = (int)floorf(x);
                int y1i = min(y0 + 1, FS_ - 1);
                int x1i = min(x0 + 1, FS_ - 1);
                float ly = y - (float)y0, lx = x - (float)x0;
                float hy = 1.0f - ly,     hx = 1.0f - lx;
                float v00 = lsc[y0  * FS_ + x0 ];
                float v01 = lsc[y0  * FS_ + x1i];
                float v10 = lsc[y1i * FS_ + x0 ];
                float v11 = lsc[y1i * FS_ + x1i];
                float val = hy * hx * v00 + hy * lx * v01 +
                            ly * hx * v10 + ly * lx * v11;
                acc += valid ? val : 0.0f;
            }
        }
        prow[(size_t)cell * C_] = __float2bfloat16(acc * 0.25f);
    }
}

// ---------------------------------------------------------------------------
// Kernel 3: pooledgemm — feat = pooled @ Wc^T, fp32 out.
//   M=9216, N=256, K=1024; both operands K-contiguous bf16, gld16 staging.
// ---------------------------------------------------------------------------
__global__ __launch_bounds__(256, 4) void pooledgemm_kernel(
    const __hip_bfloat16* __restrict__ A,    // pooled (9216 x 1024)
    const __hip_bfloat16* __restrict__ Bm,   // Wc (256 x 1024)
    float* __restrict__ Cout)                // feat (9216 x 256) fp32
{
    const int tid = threadIdx.x;
    const int wave = tid >> 6, lane = tid & 63;
    const int r0 = blockIdx.y * 64, n0 = blockIdx.x * 64;
    const int wm = (wave >> 1) * 32, wn = (wave & 1) * 32;
    const int m16 = lane & 15, quad = lane >> 4;
    const int K = C_;
    __shared__ __align__(16) __hip_bfloat16 As[64 * 64];
    __shared__ __align__(16) __hip_bfloat16 Bs[64 * 64];

    f32x4 acc[2][2];
    #pragma unroll
    for (int i = 0; i < 2; ++i)
        #pragma unroll
        for (int j = 0; j < 2; ++j)
            acc[i][j] = (f32x4){0.f, 0.f, 0.f, 0.f};

    const int qa = wave * 64 + lane;                 // 0..255
    const int ms0 = qa >> 3, cs0 = (qa & 7) ^ (ms0 & 7);
    const int qb1 = qa + 256;
    const int ms1 = qb1 >> 3, cs1 = (qb1 & 7) ^ (ms1 & 7);
    const size_t rA0 = (size_t)(r0 + ms0) * K + cs0 * 8;
    const size_t rA1 = (size_t)(r0 + ms1) * K + cs1 * 8;
    const size_t rB0 = (size_t)(n0 + ms0) * K + cs0 * 8;
    const size_t rB1 = (size_t)(n0 + ms1) * K + cs1 * 8;

    for (int k0 = 0; k0 < K; k0 += 64) {
        gld16(A  + rA0 + k0, &As[wave * 512]);
        gld16(Bm + rB0 + k0, &Bs[wave * 512]);
        gld16(A  + rA1 + k0, &As[2048 + wave * 512]);
        gld16(Bm + rB1 + k0, &Bs[2048 + wave * 512]);
        __syncthreads();
        #pragma unroll
        for (int ks = 0; ks < 2; ++ks) {
            bf16x8 af[2], bfv[2];
            #pragma unroll
            for (int t = 0; t < 2; ++t) {
                int m = wm + t * 16 + m16;
                int cp = (ks * 4 + quad) ^ (m & 7);
                af[t] = *(const bf16x8*)&As[(m * 8 + cp) * 8];
                int n = wn + t * 16 + m16;
                int cq = (ks * 4 + quad) ^ (n & 7);
                bfv[t] = *(const bf16x8*)&Bs[(n * 8 + cq) * 8];
            }
            #pragma unroll
            for (int i = 0; i < 2; ++i)
                #pragma unroll
                for (int j = 0; j < 2; ++j)
                    acc[i][j] = __builtin_amdgcn_mfma_f32_16x16x32_bf16(
                        af[i], bfv[j], acc[i][j], 0, 0, 0);
        }
        __syncthreads();
    }

    #pragma unroll
    for (int i = 0; i < 2; ++i) {
        #pragma unroll
        for (int j = 0; j < 2; ++j) {
            int col = n0 + wn + j * 16 + m16;
            int rbase = r0 + wm + i * 16 + quad * 4;
            #pragma unroll
            for (int g = 0; g < 4; ++g)
                Cout[(size_t)(rbase + g) * 256 + col] = acc[i][j][g];
        }
    }
}

// ---------------------------------------------------------------------------
// MFMA GEMM (fc1): h1 = relu(diff @ fc1_wp^T + b). 32x64 tile, BK=64.
// ---------------------------------------------------------------------------
__global__ __launch_bounds__(256, 4) void fc1_gemm_kernel(
    const __hip_bfloat16* __restrict__ A,    // diff (1024 x 2304)
    const __hip_bfloat16* __restrict__ Bm,   // fc1_wp (1024 x 2304)
    const float* __restrict__ bias,
    float* __restrict__ C)                   // h1 (1024 x 1024)
{
    const int tid = threadIdx.x;
    const int wave = tid >> 6, lane = tid & 63;
    const int r0 = blockIdx.y * 32, n0 = blockIdx.x * 64;
    const int wm = (wave >> 1) * 16, wn = (wave & 1) * 32;
    const int m16 = lane & 15, quad = lane >> 4;
    const int K = FEATD_;
    __shared__ __align__(16) __hip_bfloat16 As[32 * 64];
    __shared__ __align__(16) __hip_bfloat16 Bs[64 * 64];

    f32x4 acc[2];
    acc[0] = (f32x4){0.f, 0.f, 0.f, 0.f};
    acc[1] = (f32x4){0.f, 0.f, 0.f, 0.f};

    const int qa = wave * 64 + lane;                 // 0..255
    const int msA = qa >> 3, csA = (qa & 7) ^ (msA & 7);
    const int qb1 = qa + 256;
    const int msB1 = qb1 >> 3, csB1 = (qb1 & 7) ^ (msB1 & 7);
    const size_t rA  = (size_t)(r0 + msA)  * K + csA  * 8;
    const size_t rB0 = (size_t)(n0 + msA)  * K + csA  * 8;
    const size_t rB1 = (size_t)(n0 + msB1) * K + csB1 * 8;

    for (int k0 = 0; k0 < K; k0 += 64) {
        gld16(A  + rA  + k0, &As[wave * 512]);
        gld16(Bm + rB0 + k0, &Bs[wave * 512]);
        gld16(Bm + rB1 + k0, &Bs[2048 + wave * 512]);
        __syncthreads();
        #pragma unroll
        for (int ks = 0; ks < 2; ++ks) {
            bf16x8 af, bfv[2];
            int m = wm + m16;
            int cp = (ks * 4 + quad) ^ (m & 7);
            af = *(const bf16x8*)&As[(m * 8 + cp) * 8];
            #pragma unroll
            for (int t = 0; t < 2; ++t) {
                int n = wn + t * 16 + m16;
                int cq = (ks * 4 + quad) ^ (n & 7);
                bfv[t] = *(const bf16x8*)&Bs[(n * 8 + cq) * 8];
            }
            #pragma unroll
            for (int j = 0; j < 2; ++j)
                acc[j] = __builtin_amdgcn_mfma_f32_16x16x32_bf16(
                    af, bfv[j], acc[j], 0, 0, 0);
        }
        __syncthreads();
    }

    #pragma unroll
    for (int j = 0; j < 2; ++j) {
        int col = n0 + wn + j * 16 + m16;
        int rbase = r0 + wm + quad * 4;
        float bv = bias[col];
        #pragma unroll
        for (int g = 0; g < 4; ++g) {
            int r = rbase + g;
            float v = acc[j][g] + bv;
            C[(size_t)r * H1_ + col] = v > 0.f ? v : 0.f;
        }
    }
}

// ---------------------------------------------------------------------------
// fc1_w (1024 x 2304 fp32, k = o*9+hw) -> bf16 permuted (k' = hw*256+o)
// ---------------------------------------------------------------------------
__global__ __launch_bounds__(256) void fc1w_perm_kernel(
    const float* __restrict__ src, __hip_bfloat16* __restrict__ dst)
{
    int h = blockIdx.x;
    int tid = threadIdx.x;
    __shared__ float buf[FEATD_];
    const float* s = src + (size_t)h * FEATD_;
    #pragma unroll
    for (int it = 0; it < 9; ++it)
        buf[it * 256 + tid] = s[it * 256 + tid];
    __syncthreads();
    __hip_bfloat16* d = dst + (size_t)h * FEATD_;
    #pragma unroll
    for (int it = 0; it < 9; ++it) {
        int dd = it * 256 + tid;       // hw = it, o = tid
        d[dd] = __float2bfloat16(buf[tid * HWC_ + it]);
    }
}

// ---------------------------------------------------------------------------
// inv[b][p] = n with pids[b][n]==p else -1
// ---------------------------------------------------------------------------
__global__ __launch_bounds__(64) void invmap_kernel(
    const int* __restrict__ pids, int* __restrict__ inv)
{
    int b = blockIdx.x;
    int p = threadIdx.x;
    if (p < P_) {
        int v = -1;
        for (int n = 0; n < N_; ++n)
            if (pids[b * N_ + n] == p) v = n;
        inv[b * P_ + p] = v;
    }
}

// ---------------------------------------------------------------------------
// mean_b[p][d] = (1/128) sum_b feat[b, inv[b][p], d]
// ---------------------------------------------------------------------------
__global__ __launch_bounds__(256) void meanb_kernel(
    const float* __restrict__ feat, const int* __restrict__ inv,
    float* __restrict__ mean_b)
{
    int p = blockIdx.x;
    int d = blockIdx.y * 256 + threadIdx.x;
    float acc = 0.0f;
    #pragma unroll 4
    for (int b = 0; b < B_; ++b) {
        int n = inv[b * P_ + p];
        if (n >= 0) acc += feat[(size_t)(b * N_ + n) * FEATD_ + d];
    }
    mean_b[(size_t)p * FEATD_ + d] = acc * (1.0f / (float)B_);
}

// ---------------------------------------------------------------------------
// diff_bf16[r][d] = bf16(mean_b[pids[r]][d] - feat[r][d])
// ---------------------------------------------------------------------------
__global__ __launch_bounds__(256) void diff_kernel(
    const float* __restrict__ feat, const float* __restrict__ mean_b,
    const int* __restrict__ pids, __hip_bfloat16* __restrict__ diff)
{
    int r = blockIdx.x;
    int pid = pids[r];
    const float* fr = feat + (size_t)r * FEATD_;
    const float* mr = mean_b + (size_t)pid * FEATD_;
    __hip_bfloat16* dr = diff + (size_t)r * FEATD_;
    for (int d = threadIdx.x; d < FEATD_; d += 256)
        dr[d] = __float2bfloat16(mr[d] - fr[d]);
}

// ---------------------------------------------------------------------------
// fc2: out[bn][o] = h1[bn] . fc2_w[o] + fc2_b[o]
// ---------------------------------------------------------------------------
__global__ __launch_bounds__(256) void fc2_kernel(
    const float* __restrict__ h1, const float* __restrict__ fc2_w,
    const float* __restrict__ fc2_b, float* __restrict__ out)
{
    int bn = blockIdx.x;
    int tid = threadIdx.x;
    __shared__ __align__(16) float row[H1_];
    __shared__ float partial[32][8];
    ((float4*)row)[tid] = ((const float4*)(h1 + (size_t)bn * H1_))[tid];
    __syncthreads();
    int o = tid >> 3, part = tid & 7;
    float acc = 0.0f;
    if (o < O_) {
        const float* wrow = fc2_w + (size_t)o * H1_ + part * 128;
        const float* hrow = row + part * 128;
        #pragma unroll 4
        for (int j = 0; j < 128; ++j) acc += hrow[j] * wrow[j];
    }
    partial[o][part] = acc;
    __syncthreads();
    if (part == 0 && o < O_) {
        float s = fc2_b[o];
        #pragma unroll
        for (int p = 0; p < 8; ++p) s += partial[o][p];
        out[(size_t)bn * O_ + o] = s;
    }
}

// ---------------------------------------------------------------------------
// Launch
// ---------------------------------------------------------------------------
extern "C" void kernel_launch(void* const* d_in, const int* in_sizes, int n_in,
                              void* d_out, int out_size, void* d_ws, size_t ws_size,
                              hipStream_t stream) {
    const float* fmap  = (const float*)d_in[0];
    const float* boxes = (const float*)d_in[1];
    const int*   pids  = (const int*)  d_in[2];
    const float* w1    = (const float*)d_in[3];
    const float* w2    = (const float*)d_in[4];
    const float* fc1_w = (const float*)d_in[5];
    const float* fc1_b = (const float*)d_in[6];
    const float* fc2_w = (const float*)d_in[7];
    const float* fc2_b = (const float*)d_in[8];
    float* out = (float*)d_out;

    // workspace layout (all 16B aligned)
    char* wsb = (char*)d_ws;
    __hip_bfloat16* Wc     = (__hip_bfloat16*)wsb;                      // 256*1024
    __hip_bfloat16* pooled = Wc + 256 * 1024;                           // 9216*1024
    __hip_bfloat16* fc1wp  = pooled + (size_t)PROWS_ * C_;              // 1024*2304
    __hip_bfloat16* diffp  = fc1wp + (size_t)H1_ * FEATD_;              // 1024*2304
    float* feat   = (float*)(diffp + (size_t)H1_ * FEATD_);             // 1024*2304
    float* mean_b = feat + (size_t)(B_ * N_) * FEATD_;                  // 20*2304
    float* h1     = mean_b + (size_t)P_ * FEATD_;                       // 1024*1024
    int*   inv    = (int*)(h1 + (size_t)(B_ * N_) * H1_);               // 128*20
    float* wpart  = (float*)(inv + 128 * P_ + 64);                      // 8*256*1024

    hipLaunchKernelGGL(wcombine_split_kernel, dim3(16, 4, 8), dim3(256), 0, stream,
                       w1, w2, wpart);
    hipLaunchKernelGGL(wc_reduce_kernel, dim3(1024), dim3(256), 0, stream,
                       wpart, Wc);
    hipLaunchKernelGGL(roipool_kernel, dim3(C_ / CCH_, 128), dim3(256), 0, stream,
                       fmap, boxes, pooled);
    hipLaunchKernelGGL(pooledgemm_kernel, dim3(4, 144), dim3(256), 0, stream,
                       pooled, Wc, feat);
    hipLaunchKernelGGL(fc1w_perm_kernel, dim3(1024), dim3(256), 0, stream,
                       fc1_w, fc1wp);
    hipLaunchKernelGGL(invmap_kernel, dim3(128), dim3(64), 0, stream,
                       pids, inv);
    hipLaunchKernelGGL(meanb_kernel, dim3(20, 9), dim3(256), 0, stream,
                       feat, inv, mean_b);
    hipLaunchKernelGGL(diff_kernel, dim3(1024), dim3(256), 0, stream,
                       feat, mean_b, pids, diffp);
    hipLaunchKernelGGL(fc1_gemm_kernel, dim3(16, 32), dim3(256), 0, stream,
                       diffp, fc1wp, fc1_b, h1);
    hipLaunchKernelGGL(fc2_kernel, dim3(1024), dim3(256), 0, stream,
                       h1, fc2_w, fc2_b, out);
}